// Round 11
// baseline (226.347 us; speedup 1.0000x reference)
//
#include <hip/hip_runtime.h>

#define NN   1024
#define NE   16384
#define HID  128
#define ND   133
#define BD   14
#define KIN  147   // ND + BD
#define NVMAX 128
#define EB   8     // edges per block in edge kernels
#define JF   8     // nodes per block in final pass (4 nodes per thread)
#define JT   2     // pairs per block in table kernel (high TLP)
#define MAXPAIRS (NVMAX * (NVMAX + 1) / 2)   // 8256
#define TB4 ((MAXPAIRS + JT - 1) / JT)       // 4128 table blocks

__device__ __forceinline__ float sigm(float x) { return 1.0f / (1.0f + expf(-x)); }

// ====== k_prep3: count+scan+fill+sort (LDS) + valid + pairs + tickets (1 block) ======

__global__ void __launch_bounds__(1024)
k_prep3(const int* __restrict__ dst, int* offs, int* elist,
        const float* __restrict__ pka, int* validIdx, int* NvP, int* vpos,
        const int* __restrict__ mask, int* pairCnt, int* pairList,
        int* lossTicket) {
    __shared__ int degS[NN];
    __shared__ int s2[NN];
    __shared__ int fillS[NN];
    __shared__ int elistS[NE];   // 64 KB
    __shared__ int vIdxS[NVMAX];
    __shared__ int maskS[NVMAX];
    __shared__ int nvS, pcS;
    int t = threadIdx.x;
    degS[t] = 0;
    float v = pka[t];
    int f = (v == v) ? 1 : 0;    // !isnan
    s2[t] = f;
    __syncthreads();
    for (int e = t; e < NE; e += NN) atomicAdd(&degS[dst[e]], 1);
    __syncthreads();
    int d0 = degS[t];
    __syncthreads();
    for (int st = 1; st < NN; st <<= 1) {
        int a = (t >= st) ? degS[t - st] : 0;
        int b = (t >= st) ? s2[t - st] : 0;
        __syncthreads();
        degS[t] += a; s2[t] += b;
        __syncthreads();
    }
    int hi = degS[t];            // inclusive = segment end
    int lo = hi - d0;            // exclusive = segment start
    offs[t] = lo;
    fillS[t] = lo;
    if (t == NN - 1) offs[NN] = hi;
    int pos = s2[t] - f;
    int ok = (f && pos < NVMAX) ? 1 : 0;
    vpos[t] = ok ? pos : -1;
    if (ok) { validIdx[pos] = t; vIdxS[pos] = t; }
    if (t == NN - 1) { int nv = (s2[t] > NVMAX) ? NVMAX : s2[t]; *NvP = nv; nvS = nv; }
    if (t == 0) { pcS = 0; *lossTicket = 0; }
    __syncthreads();
    // CSR fill into LDS (order nondeterministic; sort canonicalizes)
    for (int e = t; e < NE; e += NN) { int p = atomicAdd(&fillS[dst[e]], 1); elistS[p] = e; }
    int Nv = nvS;
    if (t < NVMAX) maskS[t] = (t < Nv) ? mask[vIdxS[t]] : 1;
    __syncthreads();
    // per-node insertion sort in LDS (thread t owns node t)
    for (int a = lo + 1; a < hi; a++) {
        int vv = elistS[a]; int b = a - 1;
        while (b >= lo && elistS[b] > vv) { elistS[b + 1] = elistS[b]; b--; }
        elistS[b + 1] = vv;
    }
    // active (v,k) pair list for the table kernel
    for (int idx = t; idx < NVMAX * NVMAX; idx += NN) {
        int vv = idx >> 7, k = idx & (NVMAX - 1);
        if (vv < Nv && k <= vv && maskS[vv] == 0) {
            int p = atomicAdd(&pcS, 1);
            pairList[p] = idx;
        }
    }
    __syncthreads();
    if (t == 0) *pairCnt = pcS;
    for (int e = t; e < NE; e += NN) elist[e] = elistS[e];
}

// ================= message passing (proven bodies; b128-batched LDS reads) =================

__global__ void k_edge_init(const float* __restrict__ x, const float* __restrict__ ea,
                            const int* __restrict__ src,
                            const float* __restrict__ Wi, const float* __restrict__ bi,
                            float* __restrict__ H0, float* __restrict__ Ht) {
    __shared__ float in[EB][KIN + 1];   // rows 592 B (16B-aligned)
    int e0 = blockIdx.x * EB;
    int h = threadIdx.x;
    for (int j = 0; j < EB; j++) {
        int e = e0 + j; int s = src[e];
        for (int k = h; k < KIN; k += HID)
            in[j][k] = (k < ND) ? x[s * ND + k] : ea[e * BD + (k - ND)];
    }
    __syncthreads();
    float acc[EB];
#pragma unroll
    for (int j = 0; j < EB; j++) acc[j] = 0.f;
    for (int k4 = 0; k4 < KIN / 4; k4++) {
        float w0 = Wi[(4 * k4 + 0) * HID + h];
        float w1 = Wi[(4 * k4 + 1) * HID + h];
        float w2 = Wi[(4 * k4 + 2) * HID + h];
        float w3 = Wi[(4 * k4 + 3) * HID + h];
#pragma unroll
        for (int j = 0; j < EB; j++) {
            const float4 m4 = *(const float4*)&in[j][4 * k4];
            acc[j] = fmaf(m4.x, w0, acc[j]);
            acc[j] = fmaf(m4.y, w1, acc[j]);
            acc[j] = fmaf(m4.z, w2, acc[j]);
            acc[j] = fmaf(m4.w, w3, acc[j]);
        }
    }
    for (int k = (KIN / 4) * 4; k < KIN; k++) {
        float w = Wi[k * HID + h];
#pragma unroll
        for (int j = 0; j < EB; j++) acc[j] = fmaf(in[j][k], w, acc[j]);
    }
    float b = bi[h];
    for (int j = 0; j < EB; j++) {
        float v = acc[j] + b;
        H0[(e0 + j) * HID + h] = v;
        Ht[(e0 + j) * HID + h] = fmaxf(v, 0.f);
    }
}

__global__ void k_segsum(const float* __restrict__ Ht, const int* __restrict__ elist,
                         const int* __restrict__ offs, float* __restrict__ agg) {
    int n = blockIdx.x; int h = threadIdx.x;
    int lo = offs[n], hi = offs[n + 1];
    float a = 0.f;
    for (int j = lo; j < hi; j++) {
        int e = elist[j];
        a += Ht[e * HID + h];
    }
    agg[n * HID + h] = a;
}

__global__ void k_edge_update(const float* __restrict__ H0, const float* __restrict__ Htin,
                              const float* __restrict__ agg,
                              const int* __restrict__ src, const int* __restrict__ rev,
                              const float* __restrict__ Wh, const float* __restrict__ bh,
                              float* __restrict__ Htout) {
    __shared__ float M[EB][HID];
    int e0 = blockIdx.x * EB;
    int h = threadIdx.x;
    for (int j = 0; j < EB; j++) {
        int e = e0 + j; int s = src[e]; int r = rev[e];
        M[j][h] = agg[s * HID + h] - Htin[r * HID + h];
    }
    __syncthreads();
    float acc[EB];
#pragma unroll
    for (int j = 0; j < EB; j++) acc[j] = 0.f;
    for (int k4 = 0; k4 < HID / 4; k4++) {
        float w0 = Wh[(4 * k4 + 0) * HID + h];
        float w1 = Wh[(4 * k4 + 1) * HID + h];
        float w2 = Wh[(4 * k4 + 2) * HID + h];
        float w3 = Wh[(4 * k4 + 3) * HID + h];
#pragma unroll
        for (int j = 0; j < EB; j++) {
            const float4 m4 = *(const float4*)&M[j][4 * k4];
            acc[j] = fmaf(m4.x, w0, acc[j]);
            acc[j] = fmaf(m4.y, w1, acc[j]);
            acc[j] = fmaf(m4.z, w2, acc[j]);
            acc[j] = fmaf(m4.w, w3, acc[j]);
        }
    }
    float b = bh[h];
    for (int j = 0; j < EB; j++) {
        int e = e0 + j;
        Htout[e * HID + h] = fmaxf(H0[e * HID + h] + acc[j] + b, 0.f);
    }
}

__global__ void k_node_embed2(const float* __restrict__ x, const float* __restrict__ Ht,
                              const int* __restrict__ elist, const int* __restrict__ offs,
                              const float* __restrict__ Wnt, const float* __restrict__ bnt,
                              const float* __restrict__ Wo, const float* __restrict__ bo,
                              float* __restrict__ Emb) {
    __shared__ float xs[ND + 1];
    __shared__ float Ms[HID];
    __shared__ float red[HID];
    int n = blockIdx.x; int h = threadIdx.x;
    for (int k = h; k < ND; k += HID) xs[k] = x[n * ND + k];
    int lo = offs[n], hi = offs[n + 1];
    float a = 0.f;
    for (int j = lo; j < hi; j++) a += Ht[elist[j] * HID + h];
    red[h] = a;
    __syncthreads();
    for (int st = 64; st > 0; st >>= 1) { if (h < st) red[h] += red[h + st]; __syncthreads(); }
    float s = red[0];
    __syncthreads();
    float Mh;
    if (s == 0.0f) {
        float t0 = 0.f, t1 = 0.f;
        int k = 0;
        for (; k + 1 < ND; k += 2) {
            t0 = fmaf(xs[k], Wnt[k * HID + h], t0);
            t1 = fmaf(xs[k + 1], Wnt[(k + 1) * HID + h], t1);
        }
        for (; k < ND; k++) t0 = fmaf(xs[k], Wnt[k * HID + h], t0);
        Mh = (t0 + t1) + bnt[h];
    } else {
        Mh = a;
    }
    Ms[h] = Mh;
    __syncthreads();
    float a0 = 0.f, a1 = 0.f;
    int k = 0;
    for (; k + 1 < ND; k += 2) {
        a0 = fmaf(xs[k], Wo[k * HID + h], a0);
        a1 = fmaf(xs[k + 1], Wo[(k + 1) * HID + h], a1);
    }
    for (; k < ND; k++) a0 = fmaf(xs[k], Wo[k * HID + h], a0);
    for (int q = 0; q < HID; q += 2) {
        a0 = fmaf(Ms[q], Wo[(ND + q) * HID + h], a0);
        a1 = fmaf(Ms[q + 1], Wo[(ND + q + 1) * HID + h], a1);
    }
    Emb[n * HID + h] = fmaxf((a0 + a1) + bo[h], 0.f);
}

// ====== k_chains3: speculative gate chains (proven) ======

__global__ void __launch_bounds__(512)
k_chains3(const float* __restrict__ Emb, const int* __restrict__ validIdx,
          const int* __restrict__ NvP,
          const float* __restrict__ Wg, const float* __restrict__ bg,
          float* __restrict__ specSt) {
    int v = blockIdx.x;
    int Nv = *NvP;
    if (v >= Nv) return;
    __shared__ float rS[HID];
    __shared__ float pS[512];
    int tid = threadIdx.x;
    int col = tid & (HID - 1);
    int slot = tid >> 7;            // 0..3, K-slice [slot*32, slot*32+32)
    float wreg[32];
#pragma unroll
    for (int q = 0; q < 32; q++)
        wreg[q] = Wg[(slot * 32 + q) * HID + col];
    float bgc = bg[col];
    int i = validIdx[v];
    if (tid < HID) rS[tid] = Emb[i * HID + tid];
    __syncthreads();
    if (slot == 0) specSt[(size_t)(v * NVMAX + 0) * HID + col] = rS[col];
    int kmax = (v < NVMAX - 1) ? v : (NVMAX - 1);
    for (int k = 1; k <= kmax; k++) {
        const float4* r4 = (const float4*)&rS[slot * 32];
        float px = 0.f, py = 0.f, pz = 0.f, pw = 0.f;
#pragma unroll
        for (int q8 = 0; q8 < 8; q8++) {
            float4 rr = r4[q8];
            px = fmaf(rr.x, wreg[4 * q8 + 0], px);
            py = fmaf(rr.y, wreg[4 * q8 + 1], py);
            pz = fmaf(rr.z, wreg[4 * q8 + 2], pz);
            pw = fmaf(rr.w, wreg[4 * q8 + 3], pw);
        }
        pS[tid] = (px + py) + (pz + pw);
        __syncthreads();
        if (slot == 0) {
            float s = ((pS[col] + pS[col + 128]) + (pS[col + 256] + pS[col + 384])) + bgc;
            float g = 1.0f - sigm(s);
            float nr = rS[col] * g;
            rS[col] = nr;
            specSt[(size_t)(v * NVMAX + k) * HID + col] = nr;
        }
        __syncthreads();
    }
}

// ====== k_table4: classifier table, JT=2 pairs/block (proven round 8) ======

__global__ void __launch_bounds__(256)
k_table4(const float* __restrict__ specSt, const int* __restrict__ pairList,
         const int* __restrict__ pairCnt,
         const float* __restrict__ Wc1, const float* __restrict__ bc1,
         const float* __restrict__ Wc2, const float* __restrict__ bc2,
         const float* __restrict__ Wc3, const float* __restrict__ bc3,
         int* __restrict__ labTab) {
    int cnt = *pairCnt;
    int base = blockIdx.x * JT;
    if (base >= cnt) return;
    int nj = cnt - base; if (nj > JT) nj = JT;
    __shared__ float rS[JT][HID];
    __shared__ float h1S[JT][256];
    __shared__ float h2S[JT][64];
    __shared__ int plS[JT];
    int tid = threadIdx.x;  // 256
    if (tid < JT) plS[tid] = (tid < nj) ? pairList[base + tid] : 0;
    __syncthreads();
    for (int idx = tid; idx < JT * HID; idx += 256) {
        int j = idx >> 7, k = idx & (HID - 1);
        rS[j][k] = (j < nj) ? specSt[(size_t)plS[j] * HID + k] : 0.f;
    }
    __syncthreads();
    {
        float a[JT];
#pragma unroll
        for (int j = 0; j < JT; j++) a[j] = 0.f;
        for (int k = 0; k < HID; k++) {
            float w = Wc1[k * 256 + tid];
#pragma unroll
            for (int j = 0; j < JT; j++) a[j] = fmaf(rS[j][k], w, a[j]);
        }
        float b1 = bc1[tid];
#pragma unroll
        for (int j = 0; j < JT; j++) h1S[j][tid] = fmaxf(a[j] + b1, 0.f);
    }
    __syncthreads();
    {
        int col = tid & 63, j = tid >> 6;   // j in 0..3; only j < nj active
        if (j < nj) {
            float acc = 0.f;
            for (int k = 0; k < 256; k++)
                acc = fmaf(h1S[j][k], Wc2[k * 64 + col], acc);
            h2S[j][col] = fmaxf(acc + bc2[col], 0.f);
        }
    }
    __syncthreads();
    if (tid < nj) {
        float l0 = bc3[0], l1 = bc3[1];
        for (int k = 0; k < 64; k++) {
            float h = h2S[tid][k];
            l0 = fmaf(h, Wc3[2 * k + 0], l0);
            l1 = fmaf(h, Wc3[2 * k + 1], l1);
        }
        labTab[plS[tid]] = (l1 > l0) ? 1 : 0;
    }
}

// ====== k_resolve2: fire-sequence walk + prefix scan (proven) ======

__global__ void k_resolve2(const int* __restrict__ validIdx, const int* __restrict__ NvP,
                           const int* __restrict__ mask, const int* __restrict__ labTab,
                           int* fireFlag, int* kPref) {
    __shared__ int vIdxS[NVMAX];
    __shared__ int maskS[NVMAX];
    __shared__ int labS[NVMAX * NVMAX];
    __shared__ int fireS[NN];
    __shared__ int scanS[NN];
    int t = threadIdx.x;
    int Nv = *NvP;
    if (t < NVMAX) {
        int vi = (t < Nv) ? validIdx[t] : 0;
        vIdxS[t] = vi;
        maskS[t] = (t < Nv) ? mask[vi] : 0;
    }
    fireS[t] = 0;
    for (int idx = t; idx < Nv * NVMAX; idx += NN) labS[idx] = labTab[idx];
    __syncthreads();
    if (t == 0) {
        int k = 0;
        for (int v = 0; v < Nv; v++) {
            int fire = (maskS[v] > 0) ? 1 : labS[v * NVMAX + k];
            fireS[vIdxS[v]] = fire;
            k += fire;
        }
    }
    __syncthreads();
    int f0 = fireS[t];
    scanS[t] = f0;
    __syncthreads();
    for (int st = 1; st < NN; st <<= 1) {
        int u = (t >= st) ? scanS[t - st] : 0;
        __syncthreads();
        scanS[t] += u;
        __syncthreads();
    }
    kPref[t] = scanS[t] - f0;
    fireFlag[t] = f0;
}

// ====== k_final7: JF=8, 4 nodes/thread gate loop (scalar conflict-free weights,
//        b128 broadcast states), k_table2-shaped MLPs, ticket loss ======

__global__ void __launch_bounds__(256)
k_final7(const float* __restrict__ Emb, const int* __restrict__ kPref,
         const int* __restrict__ fireFlag, const int* __restrict__ mask,
         const float* __restrict__ pka, const int* __restrict__ vpos,
         const int* __restrict__ labTab,
         const float* __restrict__ Wg, const float* __restrict__ bg,
         const float* __restrict__ Wc1, const float* __restrict__ bc1,
         const float* __restrict__ Wc2, const float* __restrict__ bc2,
         const float* __restrict__ Wc3, const float* __restrict__ bc3,
         const float* __restrict__ Wr1, const float* __restrict__ br1,
         const float* __restrict__ Wr2, const float* __restrict__ br2,
         const float* __restrict__ Wr3, const float* __restrict__ br3,
         float* __restrict__ outLabels, float* __restrict__ outPreds,
         float* __restrict__ ceArr, float* __restrict__ regArr,
         float* __restrict__ corArr, float* __restrict__ outLoss,
         int* __restrict__ lossTicket) {
    __shared__ float WgS[HID * HID];          // 64 KB, layout [q*128 + col] (bank = col%32)
    __shared__ __align__(16) float rS[JF][HID];
    __shared__ float h1S[JF][256];
    __shared__ float h2S[JF][64];
    __shared__ float lgS[JF][2];
    __shared__ float prS[JF];
    __shared__ int kcS[JF];
    __shared__ int tkS;
    int tid = threadIdx.x;  // 256
    int i0 = blockIdx.x * JF;

    const float4* Wg4 = (const float4*)Wg;
    float4* Ws4 = (float4*)WgS;
    for (int idx = tid; idx < HID * HID / 4; idx += 256) Ws4[idx] = Wg4[idx];
    for (int idx = tid; idx < JF * HID; idx += 256) {
        int j = idx >> 7, c = idx & (HID - 1);
        rS[j][c] = Emb[(i0 + j) * HID + c];
    }
    if (tid < JF) kcS[tid] = kPref[i0 + tid];
    __syncthreads();
    int kc[JF]; int maxkc = 0;
#pragma unroll
    for (int j = 0; j < JF; j++) { kc[j] = kcS[j]; if (kc[j] > maxkc) maxkc = kc[j]; }

    // gate loop: thread (col, slot) handles nodes slot*4 .. slot*4+3
    int col = tid & (HID - 1);
    int slot = tid >> 7;            // 0 or 1
    int jb = slot * 4;
    float bgc = bg[col];
    for (int t = 0; t < maxkc; t++) {
        float a0_[4], a1_[4], a2_[4], a3_[4];
#pragma unroll
        for (int j = 0; j < 4; j++) { a0_[j] = 0.f; a1_[j] = 0.f; a2_[j] = 0.f; a3_[j] = 0.f; }
        for (int q4 = 0; q4 < 32; q4++) {
            float w0 = WgS[(4 * q4 + 0) * HID + col];
            float w1 = WgS[(4 * q4 + 1) * HID + col];
            float w2 = WgS[(4 * q4 + 2) * HID + col];
            float w3 = WgS[(4 * q4 + 3) * HID + col];
#pragma unroll
            for (int j = 0; j < 4; j++) {
                const float4 r4 = *(const float4*)&rS[jb + j][4 * q4];
                a0_[j] = fmaf(r4.x, w0, a0_[j]);
                a1_[j] = fmaf(r4.y, w1, a1_[j]);
                a2_[j] = fmaf(r4.z, w2, a2_[j]);
                a3_[j] = fmaf(r4.w, w3, a3_[j]);
            }
        }
        float g[4];
#pragma unroll
        for (int j = 0; j < 4; j++)
            g[j] = 1.0f - sigm(((a0_[j] + a1_[j]) + (a2_[j] + a3_[j])) + bgc);
        __syncthreads();
#pragma unroll
        for (int j = 0; j < 4; j++)
            if (t < kc[jb + j]) rS[jb + j][col] *= g[j];
        __syncthreads();
    }

    {   // classifier layer1: a[8], col = tid, sequential k (k_table2-proven shape)
        float a[JF];
#pragma unroll
        for (int j = 0; j < JF; j++) a[j] = 0.f;
        for (int k = 0; k < HID; k++) {
            float w = Wc1[k * 256 + tid];
#pragma unroll
            for (int j = 0; j < JF; j++) a[j] = fmaf(rS[j][k], w, a[j]);
        }
        float b = bc1[tid];
#pragma unroll
        for (int j = 0; j < JF; j++) h1S[j][tid] = fmaxf(a[j] + b, 0.f);
    }
    __syncthreads();
    {   // layer2: 4 groups x 64 cols, each group handles node pair (g2, g2+1)
        int c2 = tid & 63, g2 = (tid >> 6) * 2;
        float b0 = 0.f, bb1 = 0.f;
        for (int k = 0; k < 256; k++) {
            float w = Wc2[k * 64 + c2];
            b0 = fmaf(h1S[g2][k], w, b0);
            bb1 = fmaf(h1S[g2 + 1][k], w, bb1);
        }
        float b2 = bc2[c2];
        h2S[g2][c2] = fmaxf(b0 + b2, 0.f);
        h2S[g2 + 1][c2] = fmaxf(bb1 + b2, 0.f);
    }
    __syncthreads();
    if (tid < 2 * JF) {
        int j = tid >> 1, c = tid & 1;
        float l = bc3[c];
        for (int k = 0; k < 64; k++) l = fmaf(h2S[j][k], Wc3[2 * k + c], l);
        lgS[j][c] = l;
    }
    __syncthreads();

    {   // regressor layer1
        float a[JF];
#pragma unroll
        for (int j = 0; j < JF; j++) a[j] = 0.f;
        for (int k = 0; k < HID; k++) {
            float w = Wr1[k * 256 + tid];
#pragma unroll
            for (int j = 0; j < JF; j++) a[j] = fmaf(rS[j][k], w, a[j]);
        }
        float b = br1[tid];
#pragma unroll
        for (int j = 0; j < JF; j++) h1S[j][tid] = fmaxf(a[j] + b, 0.f);
    }
    __syncthreads();
    {
        int c2 = tid & 63, g2 = (tid >> 6) * 2;
        float b0 = 0.f, bb1 = 0.f;
        for (int k = 0; k < 256; k++) {
            float w = Wr2[k * 64 + c2];
            b0 = fmaf(h1S[g2][k], w, b0);
            bb1 = fmaf(h1S[g2 + 1][k], w, bb1);
        }
        float b2 = br2[c2];
        h2S[g2][c2] = fmaxf(b0 + b2, 0.f);
        h2S[g2 + 1][c2] = fmaxf(bb1 + b2, 0.f);
    }
    __syncthreads();
    if (tid < JF) {
        float pr = br3[0];
        for (int k = 0; k < 64; k++) pr = fmaf(h2S[tid][k], Wr3[k], pr);
        prS[tid] = pr;
    }
    __syncthreads();

    if (tid < JF) {
        int j = tid, i = i0 + j;
        float l0 = lgS[j][0], l1 = lgS[j][1];
        int compLab = (l1 > l0) ? 1 : 0;
        int vp = vpos[i];
        int label = (vp >= 0 && mask[i] == 0) ? labTab[vp * NVMAX + kc[j]] : compLab;
        int target = (mask[i] > 0) ? 1 : 0;
        float mx = fmaxf(l0, l1);
        float lse = mx + logf(expf(l0 - mx) + expf(l1 - mx));
        float ce = lse - ((target == 1) ? l1 : l0);
        int reg_cond = (label == 1) || (mask[i] > 0);
        float p = sigm(prS[j]);
        p = fminf(fmaxf(p, 0.f), 14.f);
        outLabels[i] = (float)label;
        outPreds[i] = reg_cond ? p : 0.f;
        ceArr[i] = ce;
        corArr[i] = (label == target) ? 1.f : 0.f;
        if (fireFlag[i]) {
            float d = p - pka[i];
            regArr[i] = d * d;
        } else {
            regArr[i] = 0.f;
        }
    }

    // ---- ticket: last block reduces loss (fixed order => deterministic) ----
    __threadfence();
    __syncthreads();
    if (tid == 0) tkS = atomicAdd(lossTicket, 1);
    __syncthreads();
    if (tkS == (NN / JF) - 1) {
        __threadfence();
        __shared__ float s[256];
        float a = ((ceArr[tid] + ceArr[tid + 256]) + (ceArr[tid + 512] + ceArr[tid + 768]));
        s[tid] = a; __syncthreads();
        for (int st = 128; st > 0; st >>= 1) { if (tid < st) s[tid] += s[tid + st]; __syncthreads(); }
        float cls = s[0]; __syncthreads();
        a = ((regArr[tid] + regArr[tid + 256]) + (regArr[tid + 512] + regArr[tid + 768]));
        s[tid] = a; __syncthreads();
        for (int st = 128; st > 0; st >>= 1) { if (tid < st) s[tid] += s[tid + st]; __syncthreads(); }
        float reg = s[0]; __syncthreads();
        a = ((corArr[tid] + corArr[tid + 256]) + (corArr[tid + 512] + corArr[tid + 768]));
        s[tid] = a; __syncthreads();
        for (int st = 128; st > 0; st >>= 1) { if (tid < st) s[tid] += s[tid + st]; __syncthreads(); }
        float cor = s[0];
        if (tid == 0) {
            outLoss[0] = cls + reg;
            outLoss[1] = cls;
            outLoss[2] = reg;
            outLoss[3] = cor / (float)NN;
        }
    }
}

// ================= launch =================

extern "C" void kernel_launch(void* const* d_in, const int* in_sizes, int n_in,
                              void* d_out, int out_size, void* d_ws, size_t ws_size,
                              hipStream_t stream) {
    const float* x    = (const float*)d_in[0];
    const float* ea   = (const float*)d_in[1];
    const float* pka  = (const float*)d_in[2];
    const int*   mask = (const int*)d_in[3];
    const int*   eidx = (const int*)d_in[4];
    const int*   rev  = (const int*)d_in[5];
    const float* Wi  = (const float*)d_in[6];  const float* bi  = (const float*)d_in[7];
    const float* Wh  = (const float*)d_in[8];  const float* bh  = (const float*)d_in[9];
    const float* Wo  = (const float*)d_in[10]; const float* bo  = (const float*)d_in[11];
    const float* Wnt = (const float*)d_in[12]; const float* bnt = (const float*)d_in[13];
    const float* Wc1 = (const float*)d_in[14]; const float* bc1 = (const float*)d_in[15];
    const float* Wc2 = (const float*)d_in[16]; const float* bc2 = (const float*)d_in[17];
    const float* Wc3 = (const float*)d_in[18]; const float* bc3 = (const float*)d_in[19];
    const float* Wr1 = (const float*)d_in[20]; const float* br1 = (const float*)d_in[21];
    const float* Wr2 = (const float*)d_in[22]; const float* br2 = (const float*)d_in[23];
    const float* Wr3 = (const float*)d_in[24]; const float* br3 = (const float*)d_in[25];
    const float* Wg  = (const float*)d_in[26]; const float* bg  = (const float*)d_in[27];

    const int* src = eidx;
    const int* dst = eidx + NE;

    char* w = (char*)d_ws;
    auto alloc = [&](size_t bytes) -> void* {
        void* p = (void*)w;
        w += ((bytes + 255) / 256) * 256;
        return p;
    };
    float* H0   = (float*)alloc((size_t)NE * HID * 4);
    float* HtA  = (float*)alloc((size_t)NE * HID * 4);
    float* HtB  = (float*)alloc((size_t)NE * HID * 4);
    float* agg  = (float*)alloc((size_t)NN * HID * 4);
    float* Emb  = (float*)alloc((size_t)NN * HID * 4);
    int* offs    = (int*)alloc((NN + 1) * 4);
    int* elist   = (int*)alloc(NE * 4);
    int* validIdx= (int*)alloc(NVMAX * 4);
    int* NvP     = (int*)alloc(16);
    int* vpos    = (int*)alloc(NN * 4);
    int* fireFlag= (int*)alloc(NN * 4);
    int* kPref   = (int*)alloc(NN * 4);
    float* specSt= (float*)alloc((size_t)NVMAX * NVMAX * HID * 4);
    int* labTab  = (int*)alloc(NVMAX * NVMAX * 4);
    int* pairCnt = (int*)alloc(16);
    int* pairList= (int*)alloc(MAXPAIRS * 4);
    int* lossTicket = (int*)alloc(16);
    float* ceArr = (float*)alloc(NN * 4);
    float* regArr= (float*)alloc(NN * 4);
    float* corArr= (float*)alloc(NN * 4);

    float* outF = (float*)d_out;  // [labels 1024][preds 1024][loss 4]

    k_prep3<<<1, NN, 0, stream>>>(dst, offs, elist, pka, validIdx, NvP, vpos,
                                  mask, pairCnt, pairList, lossTicket);

    k_edge_init<<<NE / EB, HID, 0, stream>>>(x, ea, src, Wi, bi, H0, HtA);
    k_segsum<<<NN, HID, 0, stream>>>(HtA, elist, offs, agg);
    k_edge_update<<<NE / EB, HID, 0, stream>>>(H0, HtA, agg, src, rev, Wh, bh, HtB);
    k_segsum<<<NN, HID, 0, stream>>>(HtB, elist, offs, agg);
    k_edge_update<<<NE / EB, HID, 0, stream>>>(H0, HtB, agg, src, rev, Wh, bh, HtA);
    k_node_embed2<<<NN, HID, 0, stream>>>(x, HtA, elist, offs, Wnt, bnt, Wo, bo, Emb);

    k_chains3<<<NVMAX, 512, 0, stream>>>(Emb, validIdx, NvP, Wg, bg, specSt);
    k_table4<<<TB4, 256, 0, stream>>>(specSt, pairList, pairCnt,
                                      Wc1, bc1, Wc2, bc2, Wc3, bc3, labTab);
    k_resolve2<<<1, NN, 0, stream>>>(validIdx, NvP, mask, labTab, fireFlag, kPref);

    k_final7<<<NN / JF, 256, 0, stream>>>(Emb, kPref, fireFlag, mask, pka, vpos, labTab,
                                          Wg, bg, Wc1, bc1, Wc2, bc2, Wc3, bc3,
                                          Wr1, br1, Wr2, br2, Wr3, br3,
                                          outF, outF + NN, ceArr, regArr, corArr,
                                          outF + 2 * NN, lossTicket);
}

// Round 12
// 215.263 us; speedup vs baseline: 1.0515x; 1.0515x over previous
//
#include <hip/hip_runtime.h>

#define NN   1024
#define NE   16384
#define HID  128
#define ND   133
#define BD   14
#define KIN  147   // ND + BD
#define NVMAX 128
#define EB   8     // edges per block in edge kernels
#define JF   4     // nodes per block in final pass
#define JT   2     // pairs per block in table kernel (high TLP)
#define MAXPAIRS (NVMAX * (NVMAX + 1) / 2)   // 8256
#define TB4 ((MAXPAIRS + JT - 1) / JT)       // 4128 table blocks

__device__ __forceinline__ float sigm(float x) { return 1.0f / (1.0f + expf(-x)); }

// ====== k_prep3: count+scan+fill+sort (LDS) + valid + pairs + tickets (1 block) ======

__global__ void __launch_bounds__(1024)
k_prep3(const int* __restrict__ dst, int* offs, int* elist,
        const float* __restrict__ pka, int* validIdx, int* NvP, int* vpos,
        const int* __restrict__ mask, int* pairCnt, int* pairList,
        int* lossTicket) {
    __shared__ int degS[NN];
    __shared__ int s2[NN];
    __shared__ int fillS[NN];
    __shared__ int elistS[NE];   // 64 KB
    __shared__ int vIdxS[NVMAX];
    __shared__ int maskS[NVMAX];
    __shared__ int nvS, pcS;
    int t = threadIdx.x;
    degS[t] = 0;
    float v = pka[t];
    int f = (v == v) ? 1 : 0;    // !isnan
    s2[t] = f;
    __syncthreads();
    for (int e = t; e < NE; e += NN) atomicAdd(&degS[dst[e]], 1);
    __syncthreads();
    int d0 = degS[t];
    __syncthreads();
    for (int st = 1; st < NN; st <<= 1) {
        int a = (t >= st) ? degS[t - st] : 0;
        int b = (t >= st) ? s2[t - st] : 0;
        __syncthreads();
        degS[t] += a; s2[t] += b;
        __syncthreads();
    }
    int hi = degS[t];            // inclusive = segment end
    int lo = hi - d0;            // exclusive = segment start
    offs[t] = lo;
    fillS[t] = lo;
    if (t == NN - 1) offs[NN] = hi;
    int pos = s2[t] - f;
    int ok = (f && pos < NVMAX) ? 1 : 0;
    vpos[t] = ok ? pos : -1;
    if (ok) { validIdx[pos] = t; vIdxS[pos] = t; }
    if (t == NN - 1) { int nv = (s2[t] > NVMAX) ? NVMAX : s2[t]; *NvP = nv; nvS = nv; }
    if (t == 0) { pcS = 0; *lossTicket = 0; }
    __syncthreads();
    // CSR fill into LDS (order nondeterministic; sort canonicalizes)
    for (int e = t; e < NE; e += NN) { int p = atomicAdd(&fillS[dst[e]], 1); elistS[p] = e; }
    int Nv = nvS;
    if (t < NVMAX) maskS[t] = (t < Nv) ? mask[vIdxS[t]] : 1;
    __syncthreads();
    // per-node insertion sort in LDS (thread t owns node t)
    for (int a = lo + 1; a < hi; a++) {
        int vv = elistS[a]; int b = a - 1;
        while (b >= lo && elistS[b] > vv) { elistS[b + 1] = elistS[b]; b--; }
        elistS[b + 1] = vv;
    }
    // active (v,k) pair list for the table kernel
    for (int idx = t; idx < NVMAX * NVMAX; idx += NN) {
        int vv = idx >> 7, k = idx & (NVMAX - 1);
        if (vv < Nv && k <= vv && maskS[vv] == 0) {
            int p = atomicAdd(&pcS, 1);
            pairList[p] = idx;
        }
    }
    __syncthreads();
    if (t == 0) *pairCnt = pcS;
    for (int e = t; e < NE; e += NN) elist[e] = elistS[e];
}

// ================= message passing (proven round-10 bodies) =================

__global__ void k_edge_init(const float* __restrict__ x, const float* __restrict__ ea,
                            const int* __restrict__ src,
                            const float* __restrict__ Wi, const float* __restrict__ bi,
                            float* __restrict__ H0, float* __restrict__ Ht) {
    __shared__ float in[EB][KIN + 1];   // rows 592 B (16B-aligned)
    int e0 = blockIdx.x * EB;
    int h = threadIdx.x;
    for (int j = 0; j < EB; j++) {
        int e = e0 + j; int s = src[e];
        for (int k = h; k < KIN; k += HID)
            in[j][k] = (k < ND) ? x[s * ND + k] : ea[e * BD + (k - ND)];
    }
    __syncthreads();
    float acc[EB];
#pragma unroll
    for (int j = 0; j < EB; j++) acc[j] = 0.f;
    for (int k4 = 0; k4 < KIN / 4; k4++) {
        float w0 = Wi[(4 * k4 + 0) * HID + h];
        float w1 = Wi[(4 * k4 + 1) * HID + h];
        float w2 = Wi[(4 * k4 + 2) * HID + h];
        float w3 = Wi[(4 * k4 + 3) * HID + h];
#pragma unroll
        for (int j = 0; j < EB; j++) {
            const float4 m4 = *(const float4*)&in[j][4 * k4];
            acc[j] = fmaf(m4.x, w0, acc[j]);
            acc[j] = fmaf(m4.y, w1, acc[j]);
            acc[j] = fmaf(m4.z, w2, acc[j]);
            acc[j] = fmaf(m4.w, w3, acc[j]);
        }
    }
    for (int k = (KIN / 4) * 4; k < KIN; k++) {
        float w = Wi[k * HID + h];
#pragma unroll
        for (int j = 0; j < EB; j++) acc[j] = fmaf(in[j][k], w, acc[j]);
    }
    float b = bi[h];
    for (int j = 0; j < EB; j++) {
        float v = acc[j] + b;
        H0[(e0 + j) * HID + h] = v;
        Ht[(e0 + j) * HID + h] = fmaxf(v, 0.f);
    }
}

__global__ void k_segsum(const float* __restrict__ Ht, const int* __restrict__ elist,
                         const int* __restrict__ offs, float* __restrict__ agg) {
    int n = blockIdx.x; int h = threadIdx.x;
    int lo = offs[n], hi = offs[n + 1];
    float a = 0.f;
    for (int j = lo; j < hi; j++) {
        int e = elist[j];
        a += Ht[e * HID + h];
    }
    agg[n * HID + h] = a;
}

__global__ void k_edge_update(const float* __restrict__ H0, const float* __restrict__ Htin,
                              const float* __restrict__ agg,
                              const int* __restrict__ src, const int* __restrict__ rev,
                              const float* __restrict__ Wh, const float* __restrict__ bh,
                              float* __restrict__ Htout) {
    __shared__ float M[EB][HID];
    int e0 = blockIdx.x * EB;
    int h = threadIdx.x;
    for (int j = 0; j < EB; j++) {
        int e = e0 + j; int s = src[e]; int r = rev[e];
        M[j][h] = agg[s * HID + h] - Htin[r * HID + h];
    }
    __syncthreads();
    float acc[EB];
#pragma unroll
    for (int j = 0; j < EB; j++) acc[j] = 0.f;
    for (int k4 = 0; k4 < HID / 4; k4++) {
        float w0 = Wh[(4 * k4 + 0) * HID + h];
        float w1 = Wh[(4 * k4 + 1) * HID + h];
        float w2 = Wh[(4 * k4 + 2) * HID + h];
        float w3 = Wh[(4 * k4 + 3) * HID + h];
#pragma unroll
        for (int j = 0; j < EB; j++) {
            const float4 m4 = *(const float4*)&M[j][4 * k4];
            acc[j] = fmaf(m4.x, w0, acc[j]);
            acc[j] = fmaf(m4.y, w1, acc[j]);
            acc[j] = fmaf(m4.z, w2, acc[j]);
            acc[j] = fmaf(m4.w, w3, acc[j]);
        }
    }
    float b = bh[h];
    for (int j = 0; j < EB; j++) {
        int e = e0 + j;
        Htout[e * HID + h] = fmaxf(H0[e * HID + h] + acc[j] + b, 0.f);
    }
}

__global__ void k_node_embed2(const float* __restrict__ x, const float* __restrict__ Ht,
                              const int* __restrict__ elist, const int* __restrict__ offs,
                              const float* __restrict__ Wnt, const float* __restrict__ bnt,
                              const float* __restrict__ Wo, const float* __restrict__ bo,
                              float* __restrict__ Emb) {
    __shared__ float xs[ND + 1];
    __shared__ float Ms[HID];
    __shared__ float red[HID];
    int n = blockIdx.x; int h = threadIdx.x;
    for (int k = h; k < ND; k += HID) xs[k] = x[n * ND + k];
    int lo = offs[n], hi = offs[n + 1];
    float a = 0.f;
    for (int j = lo; j < hi; j++) a += Ht[elist[j] * HID + h];
    red[h] = a;
    __syncthreads();
    for (int st = 64; st > 0; st >>= 1) { if (h < st) red[h] += red[h + st]; __syncthreads(); }
    float s = red[0];
    __syncthreads();
    float Mh;
    if (s == 0.0f) {
        float t0 = 0.f, t1 = 0.f;
        int k = 0;
        for (; k + 1 < ND; k += 2) {
            t0 = fmaf(xs[k], Wnt[k * HID + h], t0);
            t1 = fmaf(xs[k + 1], Wnt[(k + 1) * HID + h], t1);
        }
        for (; k < ND; k++) t0 = fmaf(xs[k], Wnt[k * HID + h], t0);
        Mh = (t0 + t1) + bnt[h];
    } else {
        Mh = a;
    }
    Ms[h] = Mh;
    __syncthreads();
    float a0 = 0.f, a1 = 0.f;
    int k = 0;
    for (; k + 1 < ND; k += 2) {
        a0 = fmaf(xs[k], Wo[k * HID + h], a0);
        a1 = fmaf(xs[k + 1], Wo[(k + 1) * HID + h], a1);
    }
    for (; k < ND; k++) a0 = fmaf(xs[k], Wo[k * HID + h], a0);
    for (int q = 0; q < HID; q += 2) {
        a0 = fmaf(Ms[q], Wo[(ND + q) * HID + h], a0);
        a1 = fmaf(Ms[q + 1], Wo[(ND + q + 1) * HID + h], a1);
    }
    Emb[n * HID + h] = fmaxf((a0 + a1) + bo[h], 0.f);
}

// ====== k_chains3: speculative gate chains (proven) ======

__global__ void __launch_bounds__(512)
k_chains3(const float* __restrict__ Emb, const int* __restrict__ validIdx,
          const int* __restrict__ NvP,
          const float* __restrict__ Wg, const float* __restrict__ bg,
          float* __restrict__ specSt) {
    int v = blockIdx.x;
    int Nv = *NvP;
    if (v >= Nv) return;
    __shared__ float rS[HID];
    __shared__ float pS[512];
    int tid = threadIdx.x;
    int col = tid & (HID - 1);
    int slot = tid >> 7;            // 0..3, K-slice [slot*32, slot*32+32)
    float wreg[32];
#pragma unroll
    for (int q = 0; q < 32; q++)
        wreg[q] = Wg[(slot * 32 + q) * HID + col];
    float bgc = bg[col];
    int i = validIdx[v];
    if (tid < HID) rS[tid] = Emb[i * HID + tid];
    __syncthreads();
    if (slot == 0) specSt[(size_t)(v * NVMAX + 0) * HID + col] = rS[col];
    int kmax = (v < NVMAX - 1) ? v : (NVMAX - 1);
    for (int k = 1; k <= kmax; k++) {
        const float4* r4 = (const float4*)&rS[slot * 32];
        float px = 0.f, py = 0.f, pz = 0.f, pw = 0.f;
#pragma unroll
        for (int q8 = 0; q8 < 8; q8++) {
            float4 rr = r4[q8];
            px = fmaf(rr.x, wreg[4 * q8 + 0], px);
            py = fmaf(rr.y, wreg[4 * q8 + 1], py);
            pz = fmaf(rr.z, wreg[4 * q8 + 2], pz);
            pw = fmaf(rr.w, wreg[4 * q8 + 3], pw);
        }
        pS[tid] = (px + py) + (pz + pw);
        __syncthreads();
        if (slot == 0) {
            float s = ((pS[col] + pS[col + 128]) + (pS[col + 256] + pS[col + 384])) + bgc;
            float g = 1.0f - sigm(s);
            float nr = rS[col] * g;
            rS[col] = nr;
            specSt[(size_t)(v * NVMAX + k) * HID + col] = nr;
        }
        __syncthreads();
    }
}

// ====== k_table4: classifier table, JT=2 pairs/block (proven round 8) ======

__global__ void __launch_bounds__(256)
k_table4(const float* __restrict__ specSt, const int* __restrict__ pairList,
         const int* __restrict__ pairCnt,
         const float* __restrict__ Wc1, const float* __restrict__ bc1,
         const float* __restrict__ Wc2, const float* __restrict__ bc2,
         const float* __restrict__ Wc3, const float* __restrict__ bc3,
         int* __restrict__ labTab) {
    int cnt = *pairCnt;
    int base = blockIdx.x * JT;
    if (base >= cnt) return;
    int nj = cnt - base; if (nj > JT) nj = JT;
    __shared__ float rS[JT][HID];
    __shared__ float h1S[JT][256];
    __shared__ float h2S[JT][64];
    __shared__ int plS[JT];
    int tid = threadIdx.x;  // 256
    if (tid < JT) plS[tid] = (tid < nj) ? pairList[base + tid] : 0;
    __syncthreads();
    for (int idx = tid; idx < JT * HID; idx += 256) {
        int j = idx >> 7, k = idx & (HID - 1);
        rS[j][k] = (j < nj) ? specSt[(size_t)plS[j] * HID + k] : 0.f;
    }
    __syncthreads();
    {
        float a[JT];
#pragma unroll
        for (int j = 0; j < JT; j++) a[j] = 0.f;
        for (int k = 0; k < HID; k++) {
            float w = Wc1[k * 256 + tid];
#pragma unroll
            for (int j = 0; j < JT; j++) a[j] = fmaf(rS[j][k], w, a[j]);
        }
        float b1 = bc1[tid];
#pragma unroll
        for (int j = 0; j < JT; j++) h1S[j][tid] = fmaxf(a[j] + b1, 0.f);
    }
    __syncthreads();
    {
        int col = tid & 63, j = tid >> 6;   // j in 0..3; only j < nj active
        if (j < nj) {
            float acc = 0.f;
            for (int k = 0; k < 256; k++)
                acc = fmaf(h1S[j][k], Wc2[k * 64 + col], acc);
            h2S[j][col] = fmaxf(acc + bc2[col], 0.f);
        }
    }
    __syncthreads();
    if (tid < nj) {
        float l0 = bc3[0], l1 = bc3[1];
        for (int k = 0; k < 64; k++) {
            float h = h2S[tid][k];
            l0 = fmaf(h, Wc3[2 * k + 0], l0);
            l1 = fmaf(h, Wc3[2 * k + 1], l1);
        }
        labTab[plS[tid]] = (l1 > l0) ? 1 : 0;
    }
}

// ====== k_resolve2: fire-sequence walk + prefix scan (proven) ======

__global__ void k_resolve2(const int* __restrict__ validIdx, const int* __restrict__ NvP,
                           const int* __restrict__ mask, const int* __restrict__ labTab,
                           int* fireFlag, int* kPref) {
    __shared__ int vIdxS[NVMAX];
    __shared__ int maskS[NVMAX];
    __shared__ int labS[NVMAX * NVMAX];
    __shared__ int fireS[NN];
    __shared__ int scanS[NN];
    int t = threadIdx.x;
    int Nv = *NvP;
    if (t < NVMAX) {
        int vi = (t < Nv) ? validIdx[t] : 0;
        vIdxS[t] = vi;
        maskS[t] = (t < Nv) ? mask[vi] : 0;
    }
    fireS[t] = 0;
    for (int idx = t; idx < Nv * NVMAX; idx += NN) labS[idx] = labTab[idx];
    __syncthreads();
    if (t == 0) {
        int k = 0;
        for (int v = 0; v < Nv; v++) {
            int fire = (maskS[v] > 0) ? 1 : labS[v * NVMAX + k];
            fireS[vIdxS[v]] = fire;
            k += fire;
        }
    }
    __syncthreads();
    int f0 = fireS[t];
    scanS[t] = f0;
    __syncthreads();
    for (int st = 1; st < NN; st <<= 1) {
        int u = (t >= st) ? scanS[t - st] : 0;
        __syncthreads();
        scanS[t] += u;
        __syncthreads();
    }
    kPref[t] = scanS[t] - f0;
    fireFlag[t] = f0;
}

// ====== k_final8: gate rounds via b128 weights (natural layout, conflict-free),
//        col-group x q-slice partial scheme; proven JF=4 MLPs; ticket loss ======

__global__ void __launch_bounds__(256)
k_final8(const float* __restrict__ Emb, const int* __restrict__ kPref,
         const int* __restrict__ fireFlag, const int* __restrict__ mask,
         const float* __restrict__ pka, const int* __restrict__ vpos,
         const int* __restrict__ labTab,
         const float* __restrict__ Wg, const float* __restrict__ bg,
         const float* __restrict__ Wc1, const float* __restrict__ bc1,
         const float* __restrict__ Wc2, const float* __restrict__ bc2,
         const float* __restrict__ Wc3, const float* __restrict__ bc3,
         const float* __restrict__ Wr1, const float* __restrict__ br1,
         const float* __restrict__ Wr2, const float* __restrict__ br2,
         const float* __restrict__ Wr3, const float* __restrict__ br3,
         float* __restrict__ outLabels, float* __restrict__ outPreds,
         float* __restrict__ ceArr, float* __restrict__ regArr,
         float* __restrict__ corArr, float* __restrict__ outLoss,
         int* __restrict__ lossTicket) {
    __shared__ __align__(16) float WgS[HID * HID];      // 64 KB natural [q*128+col]
    __shared__ __align__(16) float rS[JF][HID];
    __shared__ __align__(16) float pS[JF][8][HID];      // 16 KB partials
    __shared__ float h1S[JF][256];
    __shared__ float h2S[JF][64];
    __shared__ float lgS[JF][2];
    __shared__ float prS[JF];
    __shared__ int kcS[JF];
    __shared__ int tkS;
    int tid = threadIdx.x;  // 256
    int i0 = blockIdx.x * JF;

    const float4* Wg4 = (const float4*)Wg;
    float4* Ws4 = (float4*)WgS;
    for (int idx = tid; idx < HID * HID / 4; idx += 256) Ws4[idx] = Wg4[idx];
    if (tid < HID) {
#pragma unroll
        for (int j = 0; j < JF; j++) rS[j][tid] = Emb[(i0 + j) * HID + tid];
    }
    if (tid < JF) kcS[tid] = kPref[i0 + tid];
    __syncthreads();
    int kc[JF]; int maxkc = 0;
#pragma unroll
    for (int j = 0; j < JF; j++) { kc[j] = kcS[j]; if (kc[j] > maxkc) maxkc = kc[j]; }

    // ---- gate rounds: thread = (colgroup cg, q-slice qs); b128 weight reads ----
    int cg = tid & 31;          // cols 4cg .. 4cg+3
    int qs = tid >> 5;          // q in [qs*16, qs*16+16)
    int q0 = qs * 16;
    int rc = tid & (HID - 1);   // reduce-phase col
    int rh = tid >> 7;          // reduce-phase node half (nodes 2rh, 2rh+1)
    float bgc = bg[rc];
    const float4* WgS4 = (const float4*)WgS;
    for (int t = 0; t < maxkc; t++) {
        float4 acc[JF];
#pragma unroll
        for (int j = 0; j < JF; j++) acc[j] = make_float4(0.f, 0.f, 0.f, 0.f);
        for (int qq = 0; qq < 16; qq += 4) {
            int q = q0 + qq;
            const float4 w0 = WgS4[(q + 0) * 32 + cg];
            const float4 w1 = WgS4[(q + 1) * 32 + cg];
            const float4 w2 = WgS4[(q + 2) * 32 + cg];
            const float4 w3 = WgS4[(q + 3) * 32 + cg];
#pragma unroll
            for (int j = 0; j < JF; j++) {
                const float4 r = *(const float4*)&rS[j][q];
                acc[j].x = fmaf(r.x, w0.x, acc[j].x);
                acc[j].x = fmaf(r.y, w1.x, acc[j].x);
                acc[j].x = fmaf(r.z, w2.x, acc[j].x);
                acc[j].x = fmaf(r.w, w3.x, acc[j].x);
                acc[j].y = fmaf(r.x, w0.y, acc[j].y);
                acc[j].y = fmaf(r.y, w1.y, acc[j].y);
                acc[j].y = fmaf(r.z, w2.y, acc[j].y);
                acc[j].y = fmaf(r.w, w3.y, acc[j].y);
                acc[j].z = fmaf(r.x, w0.z, acc[j].z);
                acc[j].z = fmaf(r.y, w1.z, acc[j].z);
                acc[j].z = fmaf(r.z, w2.z, acc[j].z);
                acc[j].z = fmaf(r.w, w3.z, acc[j].z);
                acc[j].w = fmaf(r.x, w0.w, acc[j].w);
                acc[j].w = fmaf(r.y, w1.w, acc[j].w);
                acc[j].w = fmaf(r.z, w2.w, acc[j].w);
                acc[j].w = fmaf(r.w, w3.w, acc[j].w);
            }
        }
#pragma unroll
        for (int j = 0; j < JF; j++)
            *(float4*)&pS[j][qs][4 * cg] = acc[j];
        __syncthreads();
        // reduce 8 slices, apply gate; thread (rc, rh) handles nodes 2rh, 2rh+1
        float nr0, nr1;
        {
            int j = 2 * rh;
            float s = pS[j][0][rc];
#pragma unroll
            for (int z = 1; z < 8; z++) s += pS[j][z][rc];
            float g = 1.0f - sigm(s + bgc);
            nr0 = (t < kc[j]) ? rS[j][rc] * g : rS[j][rc];
        }
        {
            int j = 2 * rh + 1;
            float s = pS[j][0][rc];
#pragma unroll
            for (int z = 1; z < 8; z++) s += pS[j][z][rc];
            float g = 1.0f - sigm(s + bgc);
            nr1 = (t < kc[j]) ? rS[j][rc] * g : rS[j][rc];
        }
        __syncthreads();
        rS[2 * rh][rc] = nr0;
        rS[2 * rh + 1][rc] = nr1;
        __syncthreads();
    }

    {   // classifier layer1 (proven JF=4 shape)
        float a[JF];
#pragma unroll
        for (int j = 0; j < JF; j++) a[j] = 0.f;
        for (int k = 0; k < HID; k++) {
            float w = Wc1[k * 256 + tid];
#pragma unroll
            for (int j = 0; j < JF; j++) a[j] = fmaf(rS[j][k], w, a[j]);
        }
        float b = bc1[tid];
#pragma unroll
        for (int j = 0; j < JF; j++) h1S[j][tid] = fmaxf(a[j] + b, 0.f);
    }
    __syncthreads();
    {
        int c2 = tid & 63, j = tid >> 6;
        float acc = 0.f;
        for (int k = 0; k < 256; k++) acc = fmaf(h1S[j][k], Wc2[k * 64 + c2], acc);
        h2S[j][c2] = fmaxf(acc + bc2[c2], 0.f);
    }
    __syncthreads();
    if (tid < 2 * JF) {
        int j = tid >> 1, c = tid & 1;
        float l = bc3[c];
        for (int k = 0; k < 64; k++) l = fmaf(h2S[j][k], Wc3[2 * k + c], l);
        lgS[j][c] = l;
    }
    __syncthreads();

    {   // regressor layer1
        float a[JF];
#pragma unroll
        for (int j = 0; j < JF; j++) a[j] = 0.f;
        for (int k = 0; k < HID; k++) {
            float w = Wr1[k * 256 + tid];
#pragma unroll
            for (int j = 0; j < JF; j++) a[j] = fmaf(rS[j][k], w, a[j]);
        }
        float b = br1[tid];
#pragma unroll
        for (int j = 0; j < JF; j++) h1S[j][tid] = fmaxf(a[j] + b, 0.f);
    }
    __syncthreads();
    {
        int c2 = tid & 63, j = tid >> 6;
        float acc = 0.f;
        for (int k = 0; k < 256; k++) acc = fmaf(h1S[j][k], Wr2[k * 64 + c2], acc);
        h2S[j][c2] = fmaxf(acc + br2[c2], 0.f);
    }
    __syncthreads();
    if (tid < JF) {
        float pr = br3[0];
        for (int k = 0; k < 64; k++) pr = fmaf(h2S[tid][k], Wr3[k], pr);
        prS[tid] = pr;
    }
    __syncthreads();

    if (tid < JF) {
        int j = tid, i = i0 + j;
        float l0 = lgS[j][0], l1 = lgS[j][1];
        int compLab = (l1 > l0) ? 1 : 0;
        int vp = vpos[i];
        int label = (vp >= 0 && mask[i] == 0) ? labTab[vp * NVMAX + kc[j]] : compLab;
        int target = (mask[i] > 0) ? 1 : 0;
        float mx = fmaxf(l0, l1);
        float lse = mx + logf(expf(l0 - mx) + expf(l1 - mx));
        float ce = lse - ((target == 1) ? l1 : l0);
        int reg_cond = (label == 1) || (mask[i] > 0);
        float p = sigm(prS[j]);
        p = fminf(fmaxf(p, 0.f), 14.f);
        outLabels[i] = (float)label;
        outPreds[i] = reg_cond ? p : 0.f;
        ceArr[i] = ce;
        corArr[i] = (label == target) ? 1.f : 0.f;
        if (fireFlag[i]) {
            float d = p - pka[i];
            regArr[i] = d * d;
        } else {
            regArr[i] = 0.f;
        }
    }

    // ---- ticket: last block reduces loss (fixed order => deterministic) ----
    __threadfence();
    __syncthreads();
    if (tid == 0) tkS = atomicAdd(lossTicket, 1);
    __syncthreads();
    if (tkS == (NN / JF) - 1) {
        __threadfence();
        __shared__ float s[256];
        float a = ((ceArr[tid] + ceArr[tid + 256]) + (ceArr[tid + 512] + ceArr[tid + 768]));
        s[tid] = a; __syncthreads();
        for (int st = 128; st > 0; st >>= 1) { if (tid < st) s[tid] += s[tid + st]; __syncthreads(); }
        float cls = s[0]; __syncthreads();
        a = ((regArr[tid] + regArr[tid + 256]) + (regArr[tid + 512] + regArr[tid + 768]));
        s[tid] = a; __syncthreads();
        for (int st = 128; st > 0; st >>= 1) { if (tid < st) s[tid] += s[tid + st]; __syncthreads(); }
        float reg = s[0]; __syncthreads();
        a = ((corArr[tid] + corArr[tid + 256]) + (corArr[tid + 512] + corArr[tid + 768]));
        s[tid] = a; __syncthreads();
        for (int st = 128; st > 0; st >>= 1) { if (tid < st) s[tid] += s[tid + st]; __syncthreads(); }
        float cor = s[0];
        if (tid == 0) {
            outLoss[0] = cls + reg;
            outLoss[1] = cls;
            outLoss[2] = reg;
            outLoss[3] = cor / (float)NN;
        }
    }
}

// ================= launch =================

extern "C" void kernel_launch(void* const* d_in, const int* in_sizes, int n_in,
                              void* d_out, int out_size, void* d_ws, size_t ws_size,
                              hipStream_t stream) {
    const float* x    = (const float*)d_in[0];
    const float* ea   = (const float*)d_in[1];
    const float* pka  = (const float*)d_in[2];
    const int*   mask = (const int*)d_in[3];
    const int*   eidx = (const int*)d_in[4];
    const int*   rev  = (const int*)d_in[5];
    const float* Wi  = (const float*)d_in[6];  const float* bi  = (const float*)d_in[7];
    const float* Wh  = (const float*)d_in[8];  const float* bh  = (const float*)d_in[9];
    const float* Wo  = (const float*)d_in[10]; const float* bo  = (const float*)d_in[11];
    const float* Wnt = (const float*)d_in[12]; const float* bnt = (const float*)d_in[13];
    const float* Wc1 = (const float*)d_in[14]; const float* bc1 = (const float*)d_in[15];
    const float* Wc2 = (const float*)d_in[16]; const float* bc2 = (const float*)d_in[17];
    const float* Wc3 = (const float*)d_in[18]; const float* bc3 = (const float*)d_in[19];
    const float* Wr1 = (const float*)d_in[20]; const float* br1 = (const float*)d_in[21];
    const float* Wr2 = (const float*)d_in[22]; const float* br2 = (const float*)d_in[23];
    const float* Wr3 = (const float*)d_in[24]; const float* br3 = (const float*)d_in[25];
    const float* Wg  = (const float*)d_in[26]; const float* bg  = (const float*)d_in[27];

    const int* src = eidx;
    const int* dst = eidx + NE;

    char* w = (char*)d_ws;
    auto alloc = [&](size_t bytes) -> void* {
        void* p = (void*)w;
        w += ((bytes + 255) / 256) * 256;
        return p;
    };
    float* H0   = (float*)alloc((size_t)NE * HID * 4);
    float* HtA  = (float*)alloc((size_t)NE * HID * 4);
    float* HtB  = (float*)alloc((size_t)NE * HID * 4);
    float* agg  = (float*)alloc((size_t)NN * HID * 4);
    float* Emb  = (float*)alloc((size_t)NN * HID * 4);
    int* offs    = (int*)alloc((NN + 1) * 4);
    int* elist   = (int*)alloc(NE * 4);
    int* validIdx= (int*)alloc(NVMAX * 4);
    int* NvP     = (int*)alloc(16);
    int* vpos    = (int*)alloc(NN * 4);
    int* fireFlag= (int*)alloc(NN * 4);
    int* kPref   = (int*)alloc(NN * 4);
    float* specSt= (float*)alloc((size_t)NVMAX * NVMAX * HID * 4);
    int* labTab  = (int*)alloc(NVMAX * NVMAX * 4);
    int* pairCnt = (int*)alloc(16);
    int* pairList= (int*)alloc(MAXPAIRS * 4);
    int* lossTicket = (int*)alloc(16);
    float* ceArr = (float*)alloc(NN * 4);
    float* regArr= (float*)alloc(NN * 4);
    float* corArr= (float*)alloc(NN * 4);

    float* outF = (float*)d_out;  // [labels 1024][preds 1024][loss 4]

    k_prep3<<<1, NN, 0, stream>>>(dst, offs, elist, pka, validIdx, NvP, vpos,
                                  mask, pairCnt, pairList, lossTicket);

    k_edge_init<<<NE / EB, HID, 0, stream>>>(x, ea, src, Wi, bi, H0, HtA);
    k_segsum<<<NN, HID, 0, stream>>>(HtA, elist, offs, agg);
    k_edge_update<<<NE / EB, HID, 0, stream>>>(H0, HtA, agg, src, rev, Wh, bh, HtB);
    k_segsum<<<NN, HID, 0, stream>>>(HtB, elist, offs, agg);
    k_edge_update<<<NE / EB, HID, 0, stream>>>(H0, HtB, agg, src, rev, Wh, bh, HtA);
    k_node_embed2<<<NN, HID, 0, stream>>>(x, HtA, elist, offs, Wnt, bnt, Wo, bo, Emb);

    k_chains3<<<NVMAX, 512, 0, stream>>>(Emb, validIdx, NvP, Wg, bg, specSt);
    k_table4<<<TB4, 256, 0, stream>>>(specSt, pairList, pairCnt,
                                      Wc1, bc1, Wc2, bc2, Wc3, bc3, labTab);
    k_resolve2<<<1, NN, 0, stream>>>(validIdx, NvP, mask, labTab, fireFlag, kPref);

    k_final8<<<NN / JF, 256, 0, stream>>>(Emb, kPref, fireFlag, mask, pka, vpos, labTab,
                                          Wg, bg, Wc1, bc1, Wc2, bc2, Wc3, bc3,
                                          Wr1, br1, Wr2, br2, Wr3, br3,
                                          outF, outF + NN, ceArr, regArr, corArr,
                                          outF + 2 * NN, lossTicket);
}